// Round 5
// baseline (172.390 us; speedup 1.0000x reference)
//
#include <hip/hip_runtime.h>
#include <math.h>

// ret[t] = r[t] + g*ret[t+1]; out = (ret-mean)/(std+eps).
// R5 = R4 structure (wave-autonomous register scan, column-major quad layout,
// lane l owns quad [256j+4l,+4) of its wave's 8x256 chunk) with the register
// fix: __launch_bounds__(256,4) relaxes the VGPR cap to 128 so all 12 loads
// issue up front (full MLP), and the epilogue uses in-place Horner suffix
// values s0..s3 (independent fmas) so raw rewards are never needed again.
// R4 failure mode: compiler chose 36 VGPRs -> loads serialized -> 1.5 TB/s.

#define GAMMA 0.99f
#define EPSN  1e-4

constexpr int BLOCK  = 256;
constexpr int WPB    = BLOCK / 64;   // waves per block
constexpr int WCHUNK = 2048;         // elements per wave
constexpr int LAW    = 1024;         // lookahead elements (gamma^1024 ~ 3e-5)
constexpr int NACC   = 32;           // atomic slot pairs

__host__ __device__ constexpr float gpow(int k) {
  double p = 1.0;
  for (int i = 0; i < k; ++i) p *= 0.99;
  return (float)p;
}
constexpr float LOG2G = -0.014499569695f;   // log2(0.99)

__device__ __forceinline__ float4 load4g(const float* __restrict__ p, long long i, long long n) {
  if (i + 3 < n) return *reinterpret_cast<const float4*>(p + i);
  float4 v = make_float4(0.f, 0.f, 0.f, 0.f);   // beyond-end == semantic zero
  if (i < n)     v.x = p[i];
  if (i + 1 < n) v.y = p[i + 1];
  if (i + 2 < n) v.z = p[i + 2];
  return v;
}

__device__ __forceinline__ void store4g(float* __restrict__ p, long long i, long long n, float4 v) {
  if (i + 3 < n) { *reinterpret_cast<float4*>(p + i) = v; return; }
  if (i < n)     p[i] = v.x;
  if (i + 1 < n) p[i + 1] = v.y;
  if (i + 2 < n) p[i + 2] = v.z;
}

__global__ __launch_bounds__(BLOCK, 4)   // cap 128 VGPR: hold 12-quad working set
void scan_stats(const float* __restrict__ r, long long n,
                double* __restrict__ acc, float* __restrict__ out) {
  const int tid  = threadIdx.x;
  const int lane = tid & 63;
  const int wv   = tid >> 6;
  const long long gw = (long long)blockIdx.x * WPB + wv;   // global wave id
  const long long W  = gw * WCHUNK;
  if (W >= n) return;   // wave-uniform exit

  // guarded butterfly multipliers: gamma^(4d), 0 where lane+d >= 64
  float gmul[6];
#pragma unroll
  for (int i = 0; i < 6; ++i) {
    const int d = 1 << i;
    gmul[i] = (lane + d < 64) ? gpow(4 << i) : 0.f;
  }
  const float w4     = exp2f((float)(4 * lane) * LOG2G);          // gamma^(4l)
  const float w4tail = exp2f((float)(4 * (63 - lane)) * LOG2G);   // gamma^(4(63-l))

  // ---- all 12 loads issued up front (8 main + 4 lookahead), coalesced ----
  float4 q[8], lq[4];
  const bool fast = (W + WCHUNK + LAW) <= n;
  if (fast) {
    const float4* p = reinterpret_cast<const float4*>(r + W) + lane;
#pragma unroll
    for (int j = 0; j < 8; ++j) q[j] = p[j * 64];
#pragma unroll
    for (int k = 0; k < 4; ++k) lq[k] = p[(8 + k) * 64];
  } else {
#pragma unroll
    for (int j = 0; j < 8; ++j) q[j] = load4g(r, W + 256 * j + 4 * lane, n);
#pragma unroll
    for (int k = 0; k < 4; ++k) lq[k] = load4g(r, W + WCHUNK + 256 * k + 4 * lane, n);
  }

  // ---- in-place Horner suffix values per quad: (r0..r3) -> (s0..s3) ----
  // s3=r3; s2=r2+g*s3; s1=r1+g*s2; s0=r0+g*s1  (s0 == quad aggregate)
  float B[8], t[4];
#pragma unroll
  for (int j = 0; j < 8; ++j) {
    q[j].z = fmaf(GAMMA, q[j].w, q[j].z);
    q[j].y = fmaf(GAMMA, q[j].z, q[j].y);
    q[j].x = fmaf(GAMMA, q[j].y, q[j].x);
    B[j] = q[j].x;                       // butterfly operand (copy of s0)
  }
#pragma unroll
  for (int k = 0; k < 4; ++k) {
    const float v = fmaf(GAMMA, fmaf(GAMMA, fmaf(GAMMA, lq[k].w, lq[k].z), lq[k].y), lq[k].x);
    t[k] = v * w4;                       // pre-weight -> xor-reduction
  }

  // ---- 6 butterfly levels: suffix scan (8 rows) + xor-sum (4 lookahead rows)
#pragma unroll
  for (int i = 0; i < 6; ++i) {
    const int d = 1 << i;
#pragma unroll
    for (int j = 0; j < 8; ++j) {
      const float u = __shfl_down(B[j], d);
      B[j] = fmaf(gmul[i], u, B[j]);
    }
#pragma unroll
    for (int k = 0; k < 4; ++k) t[k] += __shfl_xor(t[k], d);
  }

  // lookahead carry at W + WCHUNK
  constexpr float G256 = gpow(256);
  const float C = fmaf(G256, fmaf(G256, fmaf(G256, t[3], t[2]), t[1]), t[0]);

  // row carries: V[j] = ret value at start of row j+1
  float V[8];
  V[7] = C;
#pragma unroll
  for (int j = 6; j >= 0; --j)
    V[j] = fmaf(G256, V[j + 1], __shfl(B[j + 1], 0));

  // ---- epilogue: o_i = s_i + gamma^(4-i) * X, all independent ----
  constexpr float G1 = gpow(1), G2 = gpow(2), G3 = gpow(3), G4 = gpow(4);
  float sm = 0.f, sq = 0.f;
#pragma unroll
  for (int j = 0; j < 8; ++j) {
    const float Sn = __shfl_down(B[j], 1);              // suffix of lanes > l
    const float X  = fmaf(w4tail, V[j], (lane < 63) ? Sn : 0.f);
    const float o0 = fmaf(G4, X, q[j].x);
    const float o1 = fmaf(G3, X, q[j].y);
    const float o2 = fmaf(G2, X, q[j].z);
    const float o3 = fmaf(G1, X, q[j].w);
    sm += (o0 + o1) + (o2 + o3);
    sq = fmaf(o0, o0, sq); sq = fmaf(o1, o1, sq);
    sq = fmaf(o2, o2, sq); sq = fmaf(o3, o3, sq);
    q[j] = make_float4(o0, o1, o2, o3);
  }

  // coalesced stores (unnormalized returns)
  if (fast) {
    float4* po = reinterpret_cast<float4*>(out + W) + lane;
#pragma unroll
    for (int j = 0; j < 8; ++j) po[j * 64] = q[j];
  } else {
#pragma unroll
    for (int j = 0; j < 8; ++j) store4g(out, W + 256 * j + 4 * lane, n, q[j]);
  }

  // wave stats reduce -> spread double atomics
#pragma unroll
  for (int i = 0; i < 6; ++i) {
    const int d = 1 << i;
    sm += __shfl_down(sm, d);
    sq += __shfl_down(sq, d);
  }
  if (lane == 0) {
    const int slot = (int)(gw & (NACC - 1)) * 2;
    atomicAdd(&acc[slot], (double)sm);
    atomicAdd(&acc[slot + 1], (double)sq);
  }
}

// pure streaming normalize, in-place on out (L3-dirty data: near-free)
__global__ void k_norm(float* __restrict__ out, long long n, const float* __restrict__ mi) {
  const float m = mi[0], inv = mi[1];
  const long long n4 = n >> 2;
  float4* p = reinterpret_cast<float4*>(out);
  long long i = (long long)blockIdx.x * blockDim.x + threadIdx.x;
  const long long stride = (long long)gridDim.x * blockDim.x;
  for (; i < n4; i += stride) {
    float4 v = p[i];
    v.x = (v.x - m) * inv; v.y = (v.y - m) * inv;
    v.z = (v.z - m) * inv; v.w = (v.w - m) * inv;
    p[i] = v;
  }
  if (blockIdx.x == 0 && threadIdx.x == 0) {   // scalar tail (n % 4)
    for (long long tt = n4 << 2; tt < n; ++tt) out[tt] = (out[tt] - m) * inv;
  }
}

__global__ void k_zero(double* __restrict__ acc) {
  const int t = threadIdx.x;
  if (t < 2 * NACC) acc[t] = 0.0;
}

__global__ void k_finalize(const double* __restrict__ acc, long long n, float* __restrict__ mi) {
  double S = 0.0, Q = 0.0;
  for (int i = 0; i < NACC; ++i) { S += acc[2 * i]; Q += acc[2 * i + 1]; }
  double mean = S / (double)n;
  double var  = Q / (double)n - mean * mean;
  if (var < 0.0) var = 0.0;
  mi[0] = (float)mean;
  mi[1] = (float)(1.0 / (sqrt(var) + EPSN));
}

extern "C" void kernel_launch(void* const* d_in, const int* in_sizes, int n_in,
                              void* d_out, int out_size, void* d_ws, size_t ws_size,
                              hipStream_t stream) {
  const float* r = (const float*)d_in[0];
  float* out = (float*)d_out;
  const long long n = (long long)in_sizes[0];

  double* acc = (double*)d_ws;                   // 64 doubles = 512 B
  float*  mi  = (float*)((char*)d_ws + 512);     // mean, inv_std

  const long long nwaves = (n + WCHUNK - 1) / WCHUNK;   // 16384 for T=2^25
  const int nblk = (int)((nwaves + WPB - 1) / WPB);     // 4096

  k_zero<<<1, 64, 0, stream>>>(acc);
  scan_stats<<<nblk, BLOCK, 0, stream>>>(r, n, acc, out);
  k_finalize<<<1, 1, 0, stream>>>(acc, n, mi);
  k_norm<<<2048, BLOCK, 0, stream>>>(out, n, mi);
}

// Round 6
// 165.117 us; speedup vs baseline: 1.0440x; 1.0440x over previous
//
#include <hip/hip_runtime.h>
#include <math.h>

// ret[t] = r[t] + g*ret[t+1]; out = (ret-mean)/(std+eps).
// R6 = R5 (wave-autonomous register scan, lane l owns quad [256j+4l,+4) of the
// wave's 8x256 chunk) + FORCED memory-level parallelism:
//   issue all 12 dwordx4 loads -> sched_barrier(0) -> s_waitcnt vmcnt(0)
//   -> sched_barrier(0) -> compute.
// R4/R5 failure: compiler sank loads to first use (VGPR=36 -> ~3 in flight ->
// 1.5 TB/s). The fence forces 12 quads live (>=48 VGPR) and one bulk wait.

#define GAMMA 0.99f
#define EPSN  1e-4

constexpr int BLOCK  = 256;
constexpr int WPB    = BLOCK / 64;   // waves per block
constexpr int WCHUNK = 2048;         // elements per wave
constexpr int LAW    = 1024;         // lookahead elements (gamma^1024 ~ 3e-5)
constexpr int NACC   = 32;           // atomic slot pairs

__host__ __device__ constexpr float gpow(int k) {
  double p = 1.0;
  for (int i = 0; i < k; ++i) p *= 0.99;
  return (float)p;
}
constexpr float LOG2G = -0.014499569695f;   // log2(0.99)

__device__ __forceinline__ float4 load4g(const float* __restrict__ p, long long i, long long n) {
  if (i + 3 < n) return *reinterpret_cast<const float4*>(p + i);
  float4 v = make_float4(0.f, 0.f, 0.f, 0.f);   // beyond-end == semantic zero
  if (i < n)     v.x = p[i];
  if (i + 1 < n) v.y = p[i + 1];
  if (i + 2 < n) v.z = p[i + 2];
  return v;
}

__device__ __forceinline__ void store4g(float* __restrict__ p, long long i, long long n, float4 v) {
  if (i + 3 < n) { *reinterpret_cast<float4*>(p + i) = v; return; }
  if (i < n)     p[i] = v.x;
  if (i + 1 < n) p[i + 1] = v.y;
  if (i + 2 < n) p[i + 2] = v.z;
}

__global__ __launch_bounds__(BLOCK, 4)   // cap 128 VGPR
void scan_stats(const float* __restrict__ r, long long n,
                double* __restrict__ acc, float* __restrict__ out) {
  const int tid  = threadIdx.x;
  const int lane = tid & 63;
  const int wv   = tid >> 6;
  const long long gw = (long long)blockIdx.x * WPB + wv;   // global wave id
  const long long W  = gw * WCHUNK;
  if (W >= n) return;   // wave-uniform exit

  // ---- all 12 loads issued up front, then ONE bulk wait (pinned) ----
  float4 q[8], lq[4];
  const bool fast = (W + WCHUNK + LAW) <= n;
  if (fast) {
    const float4* p = reinterpret_cast<const float4*>(r + W) + lane;
#pragma unroll
    for (int j = 0; j < 8; ++j) q[j] = p[j * 64];
#pragma unroll
    for (int k = 0; k < 4; ++k) lq[k] = p[(8 + k) * 64];
    __builtin_amdgcn_sched_barrier(0);            // loads may not sink below
    asm volatile("s_waitcnt vmcnt(0)" ::: "memory");
    __builtin_amdgcn_sched_barrier(0);            // uses may not hoist above
  } else {
#pragma unroll
    for (int j = 0; j < 8; ++j) q[j] = load4g(r, W + 256 * j + 4 * lane, n);
#pragma unroll
    for (int k = 0; k < 4; ++k) lq[k] = load4g(r, W + WCHUNK + 256 * k + 4 * lane, n);
  }

  // guarded butterfly multipliers: gamma^(4d), 0 where lane+d >= 64
  float gmul[6];
#pragma unroll
  for (int i = 0; i < 6; ++i) {
    const int d = 1 << i;
    gmul[i] = (lane + d < 64) ? gpow(4 << i) : 0.f;
  }
  const float w4     = exp2f((float)(4 * lane) * LOG2G);          // gamma^(4l)
  const float w4tail = exp2f((float)(4 * (63 - lane)) * LOG2G);   // gamma^(4(63-l))

  // ---- in-place Horner suffix values per quad: (r0..r3) -> (s0..s3) ----
  float B[8], t[4];
#pragma unroll
  for (int j = 0; j < 8; ++j) {
    q[j].z = fmaf(GAMMA, q[j].w, q[j].z);
    q[j].y = fmaf(GAMMA, q[j].z, q[j].y);
    q[j].x = fmaf(GAMMA, q[j].y, q[j].x);
    B[j] = q[j].x;                       // butterfly operand (copy of s0)
  }
#pragma unroll
  for (int k = 0; k < 4; ++k) {
    const float v = fmaf(GAMMA, fmaf(GAMMA, fmaf(GAMMA, lq[k].w, lq[k].z), lq[k].y), lq[k].x);
    t[k] = v * w4;                       // pre-weight -> xor-reduction
  }

  // ---- 6 butterfly levels: suffix scan (8 rows) + xor-sum (4 LA rows) ----
#pragma unroll
  for (int i = 0; i < 6; ++i) {
    const int d = 1 << i;
#pragma unroll
    for (int j = 0; j < 8; ++j) {
      const float u = __shfl_down(B[j], d);
      B[j] = fmaf(gmul[i], u, B[j]);
    }
#pragma unroll
    for (int k = 0; k < 4; ++k) t[k] += __shfl_xor(t[k], d);
  }

  // lookahead carry at W + WCHUNK
  constexpr float G256 = gpow(256);
  const float C = fmaf(G256, fmaf(G256, fmaf(G256, t[3], t[2]), t[1]), t[0]);

  // row totals: 8 independent broadcasts, then 7 dependent scalar fmas
  float rt[8];
#pragma unroll
  for (int j = 0; j < 8; ++j) rt[j] = __shfl(B[j], 0);
  float V[8];
  V[7] = C;
#pragma unroll
  for (int j = 6; j >= 0; --j) V[j] = fmaf(G256, V[j + 1], rt[j + 1]);

  // ---- epilogue: o_i = s_i + gamma^(4-i) * X, all independent ----
  constexpr float G1 = gpow(1), G2 = gpow(2), G3 = gpow(3), G4 = gpow(4);
  float sm = 0.f, sq = 0.f;
#pragma unroll
  for (int j = 0; j < 8; ++j) {
    const float Sn = __shfl_down(B[j], 1);              // suffix of lanes > l
    const float X  = fmaf(w4tail, V[j], (lane < 63) ? Sn : 0.f);
    const float o0 = fmaf(G4, X, q[j].x);
    const float o1 = fmaf(G3, X, q[j].y);
    const float o2 = fmaf(G2, X, q[j].z);
    const float o3 = fmaf(G1, X, q[j].w);
    sm += (o0 + o1) + (o2 + o3);
    sq = fmaf(o0, o0, sq); sq = fmaf(o1, o1, sq);
    sq = fmaf(o2, o2, sq); sq = fmaf(o3, o3, sq);
    q[j] = make_float4(o0, o1, o2, o3);
  }

  // coalesced stores (unnormalized returns)
  if (fast) {
    float4* po = reinterpret_cast<float4*>(out + W) + lane;
#pragma unroll
    for (int j = 0; j < 8; ++j) po[j * 64] = q[j];
  } else {
#pragma unroll
    for (int j = 0; j < 8; ++j) store4g(out, W + 256 * j + 4 * lane, n, q[j]);
  }

  // wave stats reduce -> spread double atomics
#pragma unroll
  for (int i = 0; i < 6; ++i) {
    const int d = 1 << i;
    sm += __shfl_down(sm, d);
    sq += __shfl_down(sq, d);
  }
  if (lane == 0) {
    const int slot = (int)(gw & (NACC - 1)) * 2;
    atomicAdd(&acc[slot], (double)sm);
    atomicAdd(&acc[slot + 1], (double)sq);
  }
}

// pure streaming normalize, in-place on out (L3-dirty data: near-free)
__global__ void k_norm(float* __restrict__ out, long long n, const float* __restrict__ mi) {
  const float m = mi[0], inv = mi[1];
  const long long n4 = n >> 2;
  float4* p = reinterpret_cast<float4*>(out);
  long long i = (long long)blockIdx.x * blockDim.x + threadIdx.x;
  const long long stride = (long long)gridDim.x * blockDim.x;
  for (; i < n4; i += stride) {
    float4 v = p[i];
    v.x = (v.x - m) * inv; v.y = (v.y - m) * inv;
    v.z = (v.z - m) * inv; v.w = (v.w - m) * inv;
    p[i] = v;
  }
  if (blockIdx.x == 0 && threadIdx.x == 0) {   // scalar tail (n % 4)
    for (long long tt = n4 << 2; tt < n; ++tt) out[tt] = (out[tt] - m) * inv;
  }
}

__global__ void k_zero(double* __restrict__ acc) {
  const int t = threadIdx.x;
  if (t < 2 * NACC) acc[t] = 0.0;
}

__global__ void k_finalize(const double* __restrict__ acc, long long n, float* __restrict__ mi) {
  double S = 0.0, Q = 0.0;
  for (int i = 0; i < NACC; ++i) { S += acc[2 * i]; Q += acc[2 * i + 1]; }
  double mean = S / (double)n;
  double var  = Q / (double)n - mean * mean;
  if (var < 0.0) var = 0.0;
  mi[0] = (float)mean;
  mi[1] = (float)(1.0 / (sqrt(var) + EPSN));
}

extern "C" void kernel_launch(void* const* d_in, const int* in_sizes, int n_in,
                              void* d_out, int out_size, void* d_ws, size_t ws_size,
                              hipStream_t stream) {
  const float* r = (const float*)d_in[0];
  float* out = (float*)d_out;
  const long long n = (long long)in_sizes[0];

  double* acc = (double*)d_ws;                   // 64 doubles = 512 B
  float*  mi  = (float*)((char*)d_ws + 512);     // mean, inv_std

  const long long nwaves = (n + WCHUNK - 1) / WCHUNK;   // 16384 for T=2^25
  const int nblk = (int)((nwaves + WPB - 1) / WPB);     // 4096

  k_zero<<<1, 64, 0, stream>>>(acc);
  scan_stats<<<nblk, BLOCK, 0, stream>>>(r, n, acc, out);
  k_finalize<<<1, 1, 0, stream>>>(acc, n, mi);
  k_norm<<<2048, BLOCK, 0, stream>>>(out, n, mi);
}

// Round 7
// 107.273 us; speedup vs baseline: 1.6070x; 1.5392x over previous
//
#include <hip/hip_runtime.h>
#include <math.h>

// ret[t] = r[t] + g*ret[t+1]; out = (ret-mean)/(std+eps).
// R7: persistent-wave software pipeline. Each wave owns SUPER=8192 contiguous
// elems = 4 chunks of 2048, processed HIGH->LOW with double-buffered prefetch:
//   prefetch(chunk c-1) ; process+store(chunk c)
// so next-chunk loads fly under current-chunk compute (loop-carried MLP --
// the only structure this compiler reliably pipelines; R4-6's one-shot burst
// was always sunk to first use, VGPR=36, 1.5 TB/s).
// High->low order: chunk c's epilogue yields ret[chunk_start] exactly -> seeds
// chunk c-1 with ZERO approximation. Only the wave's top chunk uses the
// gamma^1024 lookahead (err ~3e-5); read amplification 1.5x -> 1.125x.

#define GAMMA 0.99f
#define EPSN  1e-4

constexpr int BLOCK  = 256;
constexpr int WPB    = BLOCK / 64;   // waves per block
constexpr int WCHUNK = 2048;         // elements per chunk (wave-round)
constexpr int CPW    = 4;            // chunks per wave
constexpr int SUPER  = WCHUNK * CPW; // 8192 contiguous elems per wave
constexpr int LAW    = 1024;         // lookahead elems (top chunk only)
constexpr int NACC   = 32;           // atomic slot pairs

__host__ __device__ constexpr float gpow(int k) {
  double p = 1.0;
  for (int i = 0; i < k; ++i) p *= 0.99;
  return (float)p;
}
constexpr float LOG2G = -0.014499569695f;   // log2(0.99)

__device__ __forceinline__ float4 load4g(const float* __restrict__ p, long long i, long long n) {
  if (i + 3 < n) return *reinterpret_cast<const float4*>(p + i);
  float4 v = make_float4(0.f, 0.f, 0.f, 0.f);   // beyond-end == semantic zero
  if (i < n)     v.x = p[i];
  if (i + 1 < n) v.y = p[i + 1];
  if (i + 2 < n) v.z = p[i + 2];
  return v;
}

__device__ __forceinline__ void store4g(float* __restrict__ p, long long i, long long n, float4 v) {
  if (i + 3 < n) { *reinterpret_cast<float4*>(p + i) = v; return; }
  if (i < n)     p[i] = v.x;
  if (i + 1 < n) p[i + 1] = v.y;
  if (i + 2 < n) p[i + 2] = v.z;
}

struct WaveCtx {
  int lane;
  float gmul[6];      // gamma^(4d), zeroed where lane+d >= 64
  float w4, w4tail;   // gamma^(4*lane), gamma^(4*(63-lane))
};

__device__ __forceinline__ void prefetch_fast(float4 (&dst)[8], const float* __restrict__ r,
                                              long long base, int lane) {
  const float4* p = reinterpret_cast<const float4*>(r + base) + lane;
#pragma unroll
  for (int j = 0; j < 8; ++j) dst[j] = p[j * 64];
  __builtin_amdgcn_sched_barrier(0);   // loads may not sink below this point
}

__device__ __forceinline__ void prefetch_guard(float4 (&dst)[8], const float* __restrict__ r,
                                               long long base, long long n, int lane) {
#pragma unroll
  for (int j = 0; j < 8; ++j) dst[j] = load4g(r, base + 256 * j + 4 * lane, n);
}

// Compute returns for one 8x256 chunk held in q (lane owns quad [256j+4l,+4)),
// seeded by exact carry C (= ret at one past chunk end). Stores results,
// accumulates stats, returns ret[chunk_start] (the next chunk's carry).
template <bool FAST>
__device__ __forceinline__ float process_store(float4 (&q)[8], float C, const WaveCtx& cx,
                                               float* __restrict__ out, long long base,
                                               long long n, float& sm, float& sq) {
  // in-place Horner suffix values per quad: (r0..r3) -> (s0..s3)
  float B[8];
#pragma unroll
  for (int j = 0; j < 8; ++j) {
    q[j].z = fmaf(GAMMA, q[j].w, q[j].z);
    q[j].y = fmaf(GAMMA, q[j].z, q[j].y);
    q[j].x = fmaf(GAMMA, q[j].y, q[j].x);
    B[j] = q[j].x;
  }
  // 6-level butterfly suffix scan per row, constant multipliers
#pragma unroll
  for (int i = 0; i < 6; ++i) {
    const int d = 1 << i;
#pragma unroll
    for (int j = 0; j < 8; ++j) {
      const float u = __shfl_down(B[j], d);
      B[j] = fmaf(cx.gmul[i], u, B[j]);
    }
  }
  constexpr float G256 = gpow(256);
  float rt[8];
#pragma unroll
  for (int j = 0; j < 8; ++j) rt[j] = __shfl(B[j], 0);   // row totals
  float V[8];
  V[7] = C;
#pragma unroll
  for (int j = 6; j >= 0; --j) V[j] = fmaf(G256, V[j + 1], rt[j + 1]);

  constexpr float G1 = gpow(1), G2 = gpow(2), G3 = gpow(3), G4 = gpow(4);
  float o00 = 0.f;
#pragma unroll
  for (int j = 0; j < 8; ++j) {
    const float Sn = __shfl_down(B[j], 1);               // suffix of lanes > l
    const float X  = fmaf(cx.w4tail, V[j], (cx.lane < 63) ? Sn : 0.f);
    const float o0 = fmaf(G4, X, q[j].x);
    const float o1 = fmaf(G3, X, q[j].y);
    const float o2 = fmaf(G2, X, q[j].z);
    const float o3 = fmaf(G1, X, q[j].w);
    sm += (o0 + o1) + (o2 + o3);
    sq = fmaf(o0, o0, sq); sq = fmaf(o1, o1, sq);
    sq = fmaf(o2, o2, sq); sq = fmaf(o3, o3, sq);
    q[j] = make_float4(o0, o1, o2, o3);
    if (j == 0) o00 = o0;
  }
  if (FAST) {
    float4* po = reinterpret_cast<float4*>(out + base) + cx.lane;
#pragma unroll
    for (int j = 0; j < 8; ++j) po[j * 64] = q[j];
  } else {
#pragma unroll
    for (int j = 0; j < 8; ++j) store4g(out, base + 256 * j + 4 * cx.lane, n, q[j]);
  }
  return __shfl(o00, 0);   // ret[chunk_start] = carry for chunk below
}

__global__ __launch_bounds__(BLOCK, 4)   // cap 128 VGPR: A+B buffers live
void scan_stats(const float* __restrict__ r, long long n,
                double* __restrict__ acc, float* __restrict__ out) {
  const int tid  = threadIdx.x;
  const int lane = tid & 63;
  const int wv   = tid >> 6;
  const long long gw = (long long)blockIdx.x * WPB + wv;
  const long long S  = gw * SUPER;
  if (S >= n) return;   // wave-uniform exit

  WaveCtx cx;
  cx.lane = lane;
#pragma unroll
  for (int i = 0; i < 6; ++i) {
    const int d = 1 << i;
    cx.gmul[i] = (lane + d < 64) ? gpow(4 << i) : 0.f;
  }
  cx.w4     = exp2f((float)(4 * lane) * LOG2G);
  cx.w4tail = exp2f((float)(4 * (63 - lane)) * LOG2G);

  constexpr float G256 = gpow(256);
  float sm = 0.f, sq = 0.f;
  float4 A[8], Bq[8];
  float C;

  const bool fast = (S + SUPER + LAW) <= n;
  if (fast) {
    // prologue: top chunk (c=3) + lookahead, one load burst
    float4 lq[4];
    const float4* p = reinterpret_cast<const float4*>(r + S + 3 * WCHUNK) + lane;
#pragma unroll
    for (int j = 0; j < 8; ++j) A[j] = p[j * 64];
#pragma unroll
    for (int k = 0; k < 4; ++k) lq[k] = p[(8 + k) * 64];
    __builtin_amdgcn_sched_barrier(0);

    float t[4];
#pragma unroll
    for (int k = 0; k < 4; ++k) {
      const float v = fmaf(GAMMA, fmaf(GAMMA, fmaf(GAMMA, lq[k].w, lq[k].z), lq[k].y), lq[k].x);
      t[k] = v * cx.w4;                 // pre-weight -> xor-reduction
    }
#pragma unroll
    for (int i = 0; i < 6; ++i) {
      const int d = 1 << i;
#pragma unroll
      for (int k = 0; k < 4; ++k) t[k] += __shfl_xor(t[k], d);
    }
    C = fmaf(G256, fmaf(G256, fmaf(G256, t[3], t[2]), t[1]), t[0]);

    // pipelined chunk loop (hand-unrolled double buffer, high -> low)
    prefetch_fast(Bq, r, S + 2 * WCHUNK, lane);
    C = process_store<true>(A,  C, cx, out, S + 3 * WCHUNK, n, sm, sq);
    prefetch_fast(A,  r, S + 1 * WCHUNK, lane);
    C = process_store<true>(Bq, C, cx, out, S + 2 * WCHUNK, n, sm, sq);
    prefetch_fast(Bq, r, S + 0 * WCHUNK, lane);
    C = process_store<true>(A,  C, cx, out, S + 1 * WCHUNK, n, sm, sq);
    C = process_store<true>(Bq, C, cx, out, S + 0 * WCHUNK, n, sm, sq);
  } else {
    // rare tail path: guarded, sequential
    float4 lq[4];
#pragma unroll
    for (int k = 0; k < 4; ++k) lq[k] = load4g(r, S + SUPER + 256 * k + 4 * lane, n);
    float t[4];
#pragma unroll
    for (int k = 0; k < 4; ++k) {
      const float v = fmaf(GAMMA, fmaf(GAMMA, fmaf(GAMMA, lq[k].w, lq[k].z), lq[k].y), lq[k].x);
      t[k] = v * cx.w4;
    }
#pragma unroll
    for (int i = 0; i < 6; ++i) {
      const int d = 1 << i;
#pragma unroll
      for (int k = 0; k < 4; ++k) t[k] += __shfl_xor(t[k], d);
    }
    C = fmaf(G256, fmaf(G256, fmaf(G256, t[3], t[2]), t[1]), t[0]);

    for (int c = CPW - 1; c >= 0; --c) {
      prefetch_guard(A, r, S + (long long)c * WCHUNK, n, lane);
      C = process_store<false>(A, C, cx, out, S + (long long)c * WCHUNK, n, sm, sq);
    }
  }

  // wave stats reduce -> spread double atomics
#pragma unroll
  for (int i = 0; i < 6; ++i) {
    const int d = 1 << i;
    sm += __shfl_down(sm, d);
    sq += __shfl_down(sq, d);
  }
  if (lane == 0) {
    const int slot = (int)(gw & (NACC - 1)) * 2;
    atomicAdd(&acc[slot], (double)sm);
    atomicAdd(&acc[slot + 1], (double)sq);
  }
}

// pure streaming normalize, in-place on out (L3-dirty data)
__global__ void k_norm(float* __restrict__ out, long long n, const float* __restrict__ mi) {
  const float m = mi[0], inv = mi[1];
  const long long n4 = n >> 2;
  float4* p = reinterpret_cast<float4*>(out);
  long long i = (long long)blockIdx.x * blockDim.x + threadIdx.x;
  const long long stride = (long long)gridDim.x * blockDim.x;
  for (; i < n4; i += stride) {
    float4 v = p[i];
    v.x = (v.x - m) * inv; v.y = (v.y - m) * inv;
    v.z = (v.z - m) * inv; v.w = (v.w - m) * inv;
    p[i] = v;
  }
  if (blockIdx.x == 0 && threadIdx.x == 0) {   // scalar tail (n % 4)
    for (long long tt = n4 << 2; tt < n; ++tt) out[tt] = (out[tt] - m) * inv;
  }
}

__global__ void k_zero(double* __restrict__ acc) {
  const int t = threadIdx.x;
  if (t < 2 * NACC) acc[t] = 0.0;
}

__global__ void k_finalize(const double* __restrict__ acc, long long n, float* __restrict__ mi) {
  double S = 0.0, Q = 0.0;
  for (int i = 0; i < NACC; ++i) { S += acc[2 * i]; Q += acc[2 * i + 1]; }
  double mean = S / (double)n;
  double var  = Q / (double)n - mean * mean;
  if (var < 0.0) var = 0.0;
  mi[0] = (float)mean;
  mi[1] = (float)(1.0 / (sqrt(var) + EPSN));
}

extern "C" void kernel_launch(void* const* d_in, const int* in_sizes, int n_in,
                              void* d_out, int out_size, void* d_ws, size_t ws_size,
                              hipStream_t stream) {
  const float* r = (const float*)d_in[0];
  float* out = (float*)d_out;
  const long long n = (long long)in_sizes[0];

  double* acc = (double*)d_ws;                   // 64 doubles = 512 B
  float*  mi  = (float*)((char*)d_ws + 512);     // mean, inv_std

  const long long nsuper = (n + SUPER - 1) / SUPER;     // 4096 for T=2^25
  const int nblk = (int)((nsuper + WPB - 1) / WPB);     // 1024

  k_zero<<<1, 64, 0, stream>>>(acc);
  scan_stats<<<nblk, BLOCK, 0, stream>>>(r, n, acc, out);
  k_finalize<<<1, 1, 0, stream>>>(acc, n, mi);
  k_norm<<<2048, BLOCK, 0, stream>>>(out, n, mi);
}

// Round 8
// 96.237 us; speedup vs baseline: 1.7913x; 1.1147x over previous
//
#include <hip/hip_runtime.h>
#include <math.h>

// ret[t] = r[t] + g*ret[t+1]; out = (ret-mean)/(std+eps).
// R8: async direct-to-LDS pipeline. The compiler sinks register-destination
// global loads to first use (R4-R7: VGPR 36-60, ~2-3 loads in flight, 1.5-1.9
// TB/s). global_load_lds is side-effecting + zero-VGPR -> cannot be sunk.
// 1 wave / 64-thread block, wave-private LDS double buffer (no barriers!),
// counted s_waitcnt vmcnt(16): current chunk's loads retired, next chunk's
// loads + previous chunk's stores stay in flight. High->low chunk order gives
// exact carry chaining; gamma^1024 lookahead only at the superchunk top.

#define GAMMA 0.99f
#define EPSN  1e-4

constexpr int WCH   = 2048;          // elements per chunk (8 rows x 256)
constexpr int ROWS  = WCH / 256;     // 8 global_load_lds per chunk
constexpr int CPW   = 8;             // chunks per wave
constexpr int SUPER = WCH * CPW;     // 16384 contiguous elems per wave
constexpr int LAW   = 1024;          // lookahead elems (err ~3e-5 raw)
constexpr int NACC  = 32;            // atomic slot pairs

__host__ __device__ constexpr float gpow(int k) {
  double p = 1.0;
  for (int i = 0; i < k; ++i) p *= 0.99;
  return (float)p;
}
constexpr float LOG2G = -0.014499569695f;   // log2(0.99)

__device__ __forceinline__ float4 load4g(const float* __restrict__ p, long long i, long long n) {
  if (i + 3 < n) return *reinterpret_cast<const float4*>(p + i);
  float4 v = make_float4(0.f, 0.f, 0.f, 0.f);   // beyond-end == semantic zero
  if (i < n)     v.x = p[i];
  if (i + 1 < n) v.y = p[i + 1];
  if (i + 2 < n) v.z = p[i + 2];
  return v;
}

__device__ __forceinline__ void store4g(float* __restrict__ p, long long i, long long n, float4 v) {
  if (i + 3 < n) { *reinterpret_cast<float4*>(p + i) = v; return; }
  if (i < n)     p[i] = v.x;
  if (i + 1 < n) p[i + 1] = v.y;
  if (i + 2 < n) p[i + 2] = v.z;
}

// async 16B/lane global->LDS. LDS dest = wave-uniform base + lane*16 (HW rule).
__device__ __forceinline__ void gll16(const float* g, float* l) {
  __builtin_amdgcn_global_load_lds(
      (const __attribute__((address_space(1))) void*)g,
      (__attribute__((address_space(3))) void*)l, 16, 0, 0);
}

#define WAITVM(N)                                               \
  do {                                                          \
    asm volatile("s_waitcnt vmcnt(" #N ")" ::: "memory");       \
    __builtin_amdgcn_sched_barrier(0);                          \
  } while (0)

// stage one 2048-elem chunk: row j -> LDS [256j..256j+256), linear copy
__device__ __forceinline__ void stage_chunk(const float* r, long long g, float* buf, int lane) {
  __builtin_amdgcn_sched_barrier(0);
#pragma unroll
  for (int j = 0; j < ROWS; ++j)
    gll16(r + g + 256 * j + 4 * lane, buf + 256 * j);
  __builtin_amdgcn_sched_barrier(0);
}

__device__ __forceinline__ void stage_la(const float* r, long long g, float* bufL, int lane) {
  __builtin_amdgcn_sched_barrier(0);
#pragma unroll
  for (int k = 0; k < 4; ++k)
    gll16(r + g + 256 * k + 4 * lane, bufL + 256 * k);
  __builtin_amdgcn_sched_barrier(0);
}

struct WaveCtx {
  int lane;
  float gmul[6];      // gamma^(4d), zeroed where lane+d >= 64
  float w4, w4tail;   // gamma^(4*lane), gamma^(4*(63-lane))
};

// lookahead reduction: value of ret at la0 assuming 0 beyond la0+LAW
__device__ __forceinline__ float la_reduce(const float4 (&lq)[4], const WaveCtx& cx) {
  float t[4];
#pragma unroll
  for (int k = 0; k < 4; ++k) {
    const float h = fmaf(GAMMA, fmaf(GAMMA, fmaf(GAMMA, lq[k].w, lq[k].z), lq[k].y), lq[k].x);
    t[k] = h * cx.w4;
  }
#pragma unroll
  for (int i = 0; i < 6; ++i) {
    const int d = 1 << i;
#pragma unroll
    for (int k = 0; k < 4; ++k) t[k] += __shfl_xor(t[k], d);
  }
  constexpr float G256 = gpow(256);
  return fmaf(G256, fmaf(G256, fmaf(G256, t[3], t[2]), t[1]), t[0]);
}

// one 8x256 chunk in q (lane owns quad [256j+4l,+4)), exact carry C in,
// stores returns, accumulates stats, returns ret[chunk_start].
template <bool FAST>
__device__ __forceinline__ float process_store(float4 (&q)[8], float C, const WaveCtx& cx,
                                               float* __restrict__ out, long long gbase,
                                               long long n, float& sm, float& sq) {
  float B[8];
#pragma unroll
  for (int j = 0; j < 8; ++j) {     // in-place Horner suffix values s0..s3
    q[j].z = fmaf(GAMMA, q[j].w, q[j].z);
    q[j].y = fmaf(GAMMA, q[j].z, q[j].y);
    q[j].x = fmaf(GAMMA, q[j].y, q[j].x);
    B[j] = q[j].x;
  }
#pragma unroll
  for (int i = 0; i < 6; ++i) {     // butterfly suffix scan, const multipliers
    const int d = 1 << i;
#pragma unroll
    for (int j = 0; j < 8; ++j) {
      const float u = __shfl_down(B[j], d);
      B[j] = fmaf(cx.gmul[i], u, B[j]);
    }
  }
  constexpr float G256 = gpow(256);
  float rt[8];
#pragma unroll
  for (int j = 0; j < 8; ++j) rt[j] = __shfl(B[j], 0);   // row totals
  float V[8];
  V[7] = C;
#pragma unroll
  for (int j = 6; j >= 0; --j) V[j] = fmaf(G256, V[j + 1], rt[j + 1]);

  constexpr float G1 = gpow(1), G2 = gpow(2), G3 = gpow(3), G4 = gpow(4);
  float o00 = 0.f;
#pragma unroll
  for (int j = 0; j < 8; ++j) {
    const float Sn = __shfl_down(B[j], 1);
    const float X  = fmaf(cx.w4tail, V[j], (cx.lane < 63) ? Sn : 0.f);
    const float o0 = fmaf(G4, X, q[j].x);
    const float o1 = fmaf(G3, X, q[j].y);
    const float o2 = fmaf(G2, X, q[j].z);
    const float o3 = fmaf(G1, X, q[j].w);
    sm += (o0 + o1) + (o2 + o3);
    sq = fmaf(o0, o0, sq); sq = fmaf(o1, o1, sq);
    sq = fmaf(o2, o2, sq); sq = fmaf(o3, o3, sq);
    q[j] = make_float4(o0, o1, o2, o3);
    if (j == 0) o00 = o0;
  }
  if (FAST) {
    float4* po = reinterpret_cast<float4*>(out + gbase) + cx.lane;
#pragma unroll
    for (int j = 0; j < 8; ++j) po[j * 64] = q[j];
  } else {
#pragma unroll
    for (int j = 0; j < 8; ++j) store4g(out, gbase + 256 * j + 4 * cx.lane, n, q[j]);
  }
  return __shfl(o00, 0);
}

// load chunk from wave-private LDS (conflict-free b128: lanes span 1024B) + process
__device__ __forceinline__ float proc_lds(const float* buf, float C, const WaveCtx& cx,
                                          float* __restrict__ out, long long gbase,
                                          float& sm, float& sq) {
  float4 q[8];
  const float4* bp = reinterpret_cast<const float4*>(buf) + cx.lane;
#pragma unroll
  for (int j = 0; j < 8; ++j) q[j] = bp[j * 64];
  return process_store<true>(q, C, cx, out, gbase, 0, sm, sq);
}

__global__ __launch_bounds__(64, 2)
void scan_stats(const float* __restrict__ r, long long n,
                double* __restrict__ acc, float* __restrict__ out) {
  __shared__ __align__(16) float bufA[WCH];
  __shared__ __align__(16) float bufB[WCH];
  __shared__ __align__(16) float bufL[LAW];

  const int lane = threadIdx.x;                 // one wave per block
  const long long S = (long long)blockIdx.x * SUPER;
  if (S >= n) return;

  WaveCtx cx;
  cx.lane = lane;
#pragma unroll
  for (int i = 0; i < 6; ++i) {
    const int d = 1 << i;
    cx.gmul[i] = (lane + d < 64) ? gpow(4 << i) : 0.f;
  }
  cx.w4     = exp2f((float)(4 * lane) * LOG2G);
  cx.w4tail = exp2f((float)(4 * (63 - lane)) * LOG2G);

  float sm = 0.f, sq = 0.f;
  float C;

  if (S + SUPER <= n) {
    // ---- prologue: top chunk + lookahead ----
    stage_chunk(r, S + 7LL * WCH, bufA, lane);
    const bool hasLA = (S + SUPER + LAW) <= n;
    if (hasLA) stage_la(r, S + SUPER, bufL, lane);
    WAITVM(0);
    if (hasLA) {
      float4 lq[4];
      const float4* lp = reinterpret_cast<const float4*>(bufL) + lane;
#pragma unroll
      for (int k = 0; k < 4; ++k) lq[k] = lp[k * 64];
      C = la_reduce(lq, cx);
    } else if (S + SUPER >= n) {
      C = 0.f;                                   // true end of array: exact
    } else {
      float4 lq[4];
#pragma unroll
      for (int k = 0; k < 4; ++k) lq[k] = load4g(r, S + SUPER + 256 * k + 4 * lane, n);
      C = la_reduce(lq, cx);
    }

    // ---- pipelined chunk loop, high -> low, counted vmcnt ----
    stage_chunk(r, S + 6LL * WCH, bufB, lane);
    C = proc_lds(bufA, C, cx, out, S + 7LL * WCH, sm, sq);
#pragma unroll 1
    for (int c = 6; c >= 2; c -= 2) {
      stage_chunk(r, S + (long long)(c - 1) * WCH, bufA, lane);
      WAITVM(16);    // retire chunk-c loads; keep 8 new loads + 8 stores flying
      C = proc_lds(bufB, C, cx, out, S + (long long)c * WCH, sm, sq);
      stage_chunk(r, S + (long long)(c - 2) * WCH, bufB, lane);
      WAITVM(16);
      C = proc_lds(bufA, C, cx, out, S + (long long)(c - 1) * WCH, sm, sq);
    }
    WAITVM(8);       // retire chunk-0 loads; keep last stores flying
    C = proc_lds(bufB, C, cx, out, S, sm, sq);
  } else {
    // ---- guarded tail superchunk (never taken for T=2^25) ----
    C = 0.f;
    for (int c = CPW - 1; c >= 0; --c) {
      const long long base = S + (long long)c * WCH;
      if (base >= n) continue;
      float4 q[8];
#pragma unroll
      for (int j = 0; j < 8; ++j) q[j] = load4g(r, base + 256 * j + 4 * lane, n);
      C = process_store<false>(q, C, cx, out, base, n, sm, sq);
    }
  }

  // wave stats reduce -> spread double atomics
#pragma unroll
  for (int i = 0; i < 6; ++i) {
    const int d = 1 << i;
    sm += __shfl_down(sm, d);
    sq += __shfl_down(sq, d);
  }
  if (lane == 0) {
    const int slot = (int)(blockIdx.x & (NACC - 1)) * 2;
    atomicAdd(&acc[slot], (double)sm);
    atomicAdd(&acc[slot + 1], (double)sq);
  }
}

// pure streaming normalize, in-place on out (L3-dirty data)
__global__ void k_norm(float* __restrict__ out, long long n, const float* __restrict__ mi) {
  const float m = mi[0], inv = mi[1];
  const long long n4 = n >> 2;
  float4* p = reinterpret_cast<float4*>(out);
  long long i = (long long)blockIdx.x * blockDim.x + threadIdx.x;
  const long long stride = (long long)gridDim.x * blockDim.x;
  for (; i < n4; i += stride) {
    float4 v = p[i];
    v.x = (v.x - m) * inv; v.y = (v.y - m) * inv;
    v.z = (v.z - m) * inv; v.w = (v.w - m) * inv;
    p[i] = v;
  }
  if (blockIdx.x == 0 && threadIdx.x == 0) {   // scalar tail (n % 4)
    for (long long tt = n4 << 2; tt < n; ++tt) out[tt] = (out[tt] - m) * inv;
  }
}

__global__ void k_zero(double* __restrict__ acc) {
  const int t = threadIdx.x;
  if (t < 2 * NACC) acc[t] = 0.0;
}

__global__ void k_finalize(const double* __restrict__ acc, long long n, float* __restrict__ mi) {
  double S = 0.0, Q = 0.0;
  for (int i = 0; i < NACC; ++i) { S += acc[2 * i]; Q += acc[2 * i + 1]; }
  double mean = S / (double)n;
  double var  = Q / (double)n - mean * mean;
  if (var < 0.0) var = 0.0;
  mi[0] = (float)mean;
  mi[1] = (float)(1.0 / (sqrt(var) + EPSN));
}

extern "C" void kernel_launch(void* const* d_in, const int* in_sizes, int n_in,
                              void* d_out, int out_size, void* d_ws, size_t ws_size,
                              hipStream_t stream) {
  const float* r = (const float*)d_in[0];
  float* out = (float*)d_out;
  const long long n = (long long)in_sizes[0];

  double* acc = (double*)d_ws;                   // 64 doubles = 512 B
  float*  mi  = (float*)((char*)d_ws + 512);     // mean, inv_std

  const long long nsuper = (n + SUPER - 1) / SUPER;   // 2048 for T=2^25

  k_zero<<<1, 64, 0, stream>>>(acc);
  scan_stats<<<(int)nsuper, 64, 0, stream>>>(r, n, acc, out);
  k_finalize<<<1, 1, 0, stream>>>(acc, n, mi);
  k_norm<<<2048, 256, 0, stream>>>(out, n, mi);
}